// Round 1
// baseline (585.618 us; speedup 1.0000x reference)
//
#include <hip/hip_runtime.h>
#include <hip/hip_bf16.h>

#define TTOT 65536  // 16 * 4096 rows

using f32x4 = __attribute__((ext_vector_type(4))) float;
using s16x8 = __attribute__((ext_vector_type(8))) short;
typedef unsigned short u16;
using u16x8 = __attribute__((ext_vector_type(8))) u16;

__device__ __forceinline__ float bf2f(u16 u) {
    union { unsigned int ui; float f; } v; v.ui = ((unsigned int)u) << 16; return v.f;
}

// ---------------- weight transpose + bf16 convert: wt[n*K+k] = w[k*N+n] ----
__global__ void wconv_t(const float* __restrict__ w, __hip_bfloat16* __restrict__ wt,
                        int K, int N) {
    int idx = blockIdx.x * 256 + threadIdx.x;
    if (idx >= K * N) return;
    int n = idx / K, k = idx - n * K;
    wt[idx] = __float2bfloat16(w[(long)k * N + n]);
}

// ---------------- ada = silu(c) @ ada_w + ada_b   (16 x 1536) --------------
__global__ __launch_bounds__(256) void ada_kernel(const float* __restrict__ c,
                                                  const float* __restrict__ ada_w,
                                                  const float* __restrict__ ada_b,
                                                  float* __restrict__ ada) {
    __shared__ float sc[16 * 256];
    int tid = threadIdx.x;
    for (int i = tid; i < 16 * 256; i += 256) {
        float v = c[i];
        sc[i] = v / (1.0f + expf(-v));
    }
    __syncthreads();
    int j = blockIdx.x * 256 + tid;   // grid = 6 -> j in [0,1536)
    float b = ada_b[j];
    for (int n = 0; n < 16; n++) {
        float acc = b;
        for (int k = 0; k < 256; k++)
            acc += sc[n * 256 + k] * ada_w[(long)k * 1536 + j];
        ada[n * 1536 + j] = acc;
    }
}

// ---------------- fused LayerNorm + modulate -> bf16 -----------------------
__global__ __launch_bounds__(256) void ln_mod(const float* __restrict__ x,
                                              const float* __restrict__ ada,
                                              int off_sh, int off_sc,
                                              __hip_bfloat16* __restrict__ out) {
    int row = blockIdx.x * 4 + (threadIdx.x >> 6);
    int lane = threadIdx.x & 63;
    const float4 v = *(const float4*)&x[(long)row * 256 + lane * 4];
    float s = v.x + v.y + v.z + v.w;
    float s2 = v.x * v.x + v.y * v.y + v.z * v.z + v.w * v.w;
#pragma unroll
    for (int o = 32; o > 0; o >>= 1) {
        s += __shfl_xor(s, o, 64);
        s2 += __shfl_xor(s2, o, 64);
    }
    float mu = s * (1.0f / 256.0f);
    float var = s2 * (1.0f / 256.0f) - mu * mu;
    float rstd = rsqrtf(var + 1e-6f);
    int nb = row >> 12;
    const float* sh = &ada[nb * 1536 + off_sh];
    const float* scp = &ada[nb * 1536 + off_sc];
    float vv[4] = {v.x, v.y, v.z, v.w};
#pragma unroll
    for (int e = 0; e < 4; e++) {
        int col = lane * 4 + e;
        float val = (vv[e] - mu) * rstd;
        val = val * (1.0f + scp[col]) + sh[col];
        out[(long)row * 256 + col] = __float2bfloat16(val);
    }
}

// ---------------- bf16 MFMA GEMM: C = A(MxK) @ Bt(NxK)^T  + epilogue -------
// MODE 0: qkv   -> outb = acc + bias                        (bf16)
// MODE 1: proj  -> outf = resid + g_msa * (acc + bias)      (f32, d_out)
// MODE 2: fc1   -> outb = gelu_tanh(acc + bias)             (bf16)
// MODE 3: fc2   -> outf = outf + g_mlp * (acc + bias)       (f32, d_out in/out)
template <int MODE>
__global__ __launch_bounds__(256) void gemm_bt(const __hip_bfloat16* __restrict__ A,
                                               const __hip_bfloat16* __restrict__ Bt,
                                               const float* __restrict__ bias,
                                               const float* __restrict__ resid,
                                               const float* __restrict__ ada,
                                               float* __restrict__ outf,
                                               __hip_bfloat16* __restrict__ outb,
                                               int M, int N, int K) {
    __shared__ u16 As[128][72];   // +8 pad: bank-conflict-free frag reads
    __shared__ u16 Bs[128][72];
    int tid = threadIdx.x;
    int lane = tid & 63;
    int wid = tid >> 6;
    int wr = wid >> 1, wc = wid & 1;
    int brow = blockIdx.y * 128;
    int bcol = blockIdx.x * 128;
    int la = lane & 15, lb = lane >> 4;

    f32x4 acc[4][4] = {};

    for (int k0 = 0; k0 < K; k0 += 64) {
        __syncthreads();
#pragma unroll
        for (int i = 0; i < 4; i++) {
            int c = tid + i * 256;          // 1024 chunks of 8 bf16
            int row = c >> 3;
            int col = (c & 7) << 3;
            *(uint4*)&As[row][col] =
                *(const uint4*)&A[(long)(brow + row) * K + k0 + col];
            *(uint4*)&Bs[row][col] =
                *(const uint4*)&Bt[(long)(bcol + row) * K + k0 + col];
        }
        __syncthreads();
#pragma unroll
        for (int kk = 0; kk < 64; kk += 32) {
            s16x8 af[4], bfr[4];
#pragma unroll
            for (int m = 0; m < 4; m++)
                af[m] = *(const s16x8*)&As[wr * 64 + m * 16 + la][kk + lb * 8];
#pragma unroll
            for (int n2 = 0; n2 < 4; n2++)
                bfr[n2] = *(const s16x8*)&Bs[wc * 64 + n2 * 16 + la][kk + lb * 8];
#pragma unroll
            for (int m = 0; m < 4; m++)
#pragma unroll
                for (int n2 = 0; n2 < 4; n2++)
                    acc[m][n2] = __builtin_amdgcn_mfma_f32_16x16x32_bf16(
                        af[m], bfr[n2], acc[m][n2], 0, 0, 0);
        }
    }

    int nb = brow >> 12;  // batch index (4096 rows/batch, 128 | 4096)
#pragma unroll
    for (int m = 0; m < 4; m++) {
#pragma unroll
        for (int n2 = 0; n2 < 4; n2++) {
#pragma unroll
            for (int r = 0; r < 4; r++) {
                int row = brow + wr * 64 + m * 16 + lb * 4 + r;
                int col = bcol + wc * 64 + n2 * 16 + la;
                float v = acc[m][n2][r] + bias[col];
                long oidx = (long)row * N + col;
                if (MODE == 0) {
                    outb[oidx] = __float2bfloat16(v);
                } else if (MODE == 1) {
                    float g = ada[nb * 1536 + 512 + col];
                    outf[oidx] = resid[oidx] + g * v;
                } else if (MODE == 2) {
                    float t = tanhf(0.7978845608028654f * (v + 0.044715f * v * v * v));
                    outb[oidx] = __float2bfloat16(0.5f * v * (1.0f + t));
                } else {
                    float g = ada[nb * 1536 + 1280 + col];
                    outf[oidx] = outf[oidx] + g * v;
                }
            }
        }
    }
}

// ---------------- window attention: 1 wave per (window, head) --------------
__global__ __launch_bounds__(64) void win_attn(const __hip_bfloat16* __restrict__ qkv,
                                               const float* __restrict__ rpb,
                                               __hip_bfloat16* __restrict__ out) {
    int bid = blockIdx.x;
    int h = bid & 7;
    int win = bid >> 3;
    int n = win >> 6;
    int wh = (win >> 3) & 7;
    int ww = win & 7;
    int t = threadIdx.x;       // query token within window
    int r1 = t >> 3, c1 = t & 7;

    __shared__ float ks[64][33];
    __shared__ float vs[64][33];
    __shared__ float bs[225];

    long seqrow = (long)n * 4096 + (wh * 8 + r1) * 64 + ww * 8 + c1;
    const u16* base = (const u16*)qkv + seqrow * 768;

    float q[32];
#pragma unroll
    for (int i = 0; i < 4; i++) {
        u16x8 qv = *(const u16x8*)(base + h * 32 + i * 8);
        u16x8 kv = *(const u16x8*)(base + 256 + h * 32 + i * 8);
        u16x8 vv = *(const u16x8*)(base + 512 + h * 32 + i * 8);
#pragma unroll
        for (int e = 0; e < 8; e++) {
            q[i * 8 + e] = bf2f(qv[e]) * 0.17677669529663687f;
            ks[t][i * 8 + e] = bf2f(kv[e]);
            vs[t][i * 8 + e] = bf2f(vv[e]);
        }
    }
    for (int i = t; i < 225; i += 64) bs[i] = rpb[i * 8 + h];
    __syncthreads();

    float s[64];
    float mx = -1e30f;
#pragma unroll
    for (int j = 0; j < 64; j++) {
        float a = 0.0f;
#pragma unroll
        for (int d = 0; d < 32; d++) a += q[d] * ks[j][d];
        int r2 = j >> 3, c2 = j & 7;
        a += bs[(r1 - r2 + 7) * 15 + (c1 - c2 + 7)];
        s[j] = a;
        mx = fmaxf(mx, a);
    }
    float l = 0.0f;
#pragma unroll
    for (int j = 0; j < 64; j++) {
        s[j] = expf(s[j] - mx);
        l += s[j];
    }
    float rl = 1.0f / l;
    float o[32] = {};
#pragma unroll
    for (int j = 0; j < 64; j++) {
        float p = s[j];
#pragma unroll
        for (int d = 0; d < 32; d++) o[d] += p * vs[j][d];
    }
    __hip_bfloat16* ob = out + seqrow * 256 + h * 32;
#pragma unroll
    for (int d = 0; d < 32; d++) ob[d] = __float2bfloat16(o[d] * rl);
}

// ---------------------------------------------------------------------------
extern "C" void kernel_launch(void* const* d_in, const int* in_sizes, int n_in,
                              void* d_out, int out_size, void* d_ws, size_t ws_size,
                              hipStream_t stream) {
    const float* x_seq  = (const float*)d_in[0];
    const float* c      = (const float*)d_in[1];
    const float* qkv_w  = (const float*)d_in[2];
    const float* qkv_b  = (const float*)d_in[3];
    const float* proj_w = (const float*)d_in[4];
    const float* proj_b = (const float*)d_in[5];
    const float* rpb    = (const float*)d_in[6];
    const float* ada_w  = (const float*)d_in[7];
    const float* ada_b  = (const float*)d_in[8];
    const float* fc1_w  = (const float*)d_in[9];
    const float* fc1_b  = (const float*)d_in[10];
    const float* fc2_w  = (const float*)d_in[11];
    const float* fc2_b  = (const float*)d_in[12];

    char* ws = (char*)d_ws;
    float* ada             = (float*)ws;                       // 96 KB
    __hip_bfloat16* qkv_wt = (__hip_bfloat16*)(ws + 131072);   // 768x256 bf16
    __hip_bfloat16* proj_wt= (__hip_bfloat16*)(ws + 524288);   // 256x256
    __hip_bfloat16* fc1_wt = (__hip_bfloat16*)(ws + 655360);   // 1024x256
    __hip_bfloat16* fc2_wt = (__hip_bfloat16*)(ws + 1179648);  // 256x1024
    __hip_bfloat16* bufA   = (__hip_bfloat16*)(ws + 2097152);  // 32 MB: xb / attn_out / xmlp
    __hip_bfloat16* bufB   = (__hip_bfloat16*)(ws + 35651584); // 128 MB: qkv / h1
    float* outf = (float*)d_out;

    wconv_t<<<(256 * 768 + 255) / 256, 256, 0, stream>>>(qkv_w, qkv_wt, 256, 768);
    wconv_t<<<(256 * 256 + 255) / 256, 256, 0, stream>>>(proj_w, proj_wt, 256, 256);
    wconv_t<<<(256 * 1024 + 255) / 256, 256, 0, stream>>>(fc1_w, fc1_wt, 256, 1024);
    wconv_t<<<(1024 * 256 + 255) / 256, 256, 0, stream>>>(fc2_w, fc2_wt, 1024, 256);

    ada_kernel<<<6, 256, 0, stream>>>(c, ada_w, ada_b, ada);

    // x_win LN+modulate (MSA) -> bufA (bf16)
    ln_mod<<<TTOT / 4, 256, 0, stream>>>(x_seq, ada, 0, 256, bufA);

    // qkv = bufA @ qkv_w + b -> bufB (bf16, 65536 x 768)
    {
        dim3 g(768 / 128, TTOT / 128);
        gemm_bt<0><<<g, 256, 0, stream>>>(bufA, qkv_wt, qkv_b, nullptr, ada,
                                          nullptr, bufB, TTOT, 768, 256);
    }
    // window attention -> bufA (bf16, 65536 x 256)
    win_attn<<<8192, 64, 0, stream>>>(bufB, rpb, bufA);

    // out1 = x_seq + g_msa * (attn @ proj_w + b) -> d_out (f32)
    {
        dim3 g(256 / 128, TTOT / 128);
        gemm_bt<1><<<g, 256, 0, stream>>>(bufA, proj_wt, proj_b, x_seq, ada,
                                          outf, nullptr, TTOT, 256, 256);
    }
    // LN+modulate (MLP) -> bufA (bf16)
    ln_mod<<<TTOT / 4, 256, 0, stream>>>(outf, ada, 768, 1024, bufA);

    // h1 = gelu(bufA @ fc1_w + b) -> bufB (bf16, 65536 x 1024)
    {
        dim3 g(1024 / 128, TTOT / 128);
        gemm_bt<2><<<g, 256, 0, stream>>>(bufA, fc1_wt, fc1_b, nullptr, ada,
                                          nullptr, bufB, TTOT, 1024, 256);
    }
    // out = out1 + g_mlp * (h1 @ fc2_w + b) -> d_out (f32)
    {
        dim3 g(256 / 128, TTOT / 128);
        gemm_bt<3><<<g, 256, 0, stream>>>(bufB, fc2_wt, fc2_b, nullptr, ada,
                                          outf, nullptr, TTOT, 256, 1024);
    }
}

// Round 3
// 490.470 us; speedup vs baseline: 1.1940x; 1.1940x over previous
//
#include <hip/hip_runtime.h>
#include <hip/hip_bf16.h>

#define TTOT 65536  // 16 * 4096 rows

using f32x4 = __attribute__((ext_vector_type(4))) float;
using s16x8 = __attribute__((ext_vector_type(8))) short;
typedef unsigned short u16;
using u16x8 = __attribute__((ext_vector_type(8))) u16;

typedef __attribute__((address_space(3))) void lds_void;
typedef __attribute__((address_space(1))) void g_void;

__device__ __forceinline__ float bf2f(u16 u) {
    union { unsigned int ui; float f; } v; v.ui = ((unsigned int)u) << 16; return v.f;
}

__device__ __forceinline__ u16 f2bf(float f) {
    return __bfloat16_as_ushort(__float2bfloat16(f));
}

// ---------------- weight transpose + bf16 convert: wt[n*K+k] = w[k*N+n] ----
__global__ void wconv_t(const float* __restrict__ w, __hip_bfloat16* __restrict__ wt,
                        int K, int N) {
    int idx = blockIdx.x * 256 + threadIdx.x;
    if (idx >= K * N) return;
    int n = idx / K, k = idx - n * K;
    wt[idx] = __float2bfloat16(w[(long)k * N + n]);
}

// ---------------- ada = silu(c) @ ada_w + ada_b   (16 x 1536) --------------
__global__ __launch_bounds__(256) void ada_kernel(const float* __restrict__ c,
                                                  const float* __restrict__ ada_w,
                                                  const float* __restrict__ ada_b,
                                                  float* __restrict__ ada) {
    __shared__ float sc[16 * 256];
    int tid = threadIdx.x;
    for (int i = tid; i < 16 * 256; i += 256) {
        float v = c[i];
        sc[i] = v / (1.0f + expf(-v));
    }
    __syncthreads();
    int j = blockIdx.x * 256 + tid;   // grid = 6 -> j in [0,1536)
    float b = ada_b[j];
    for (int n = 0; n < 16; n++) {
        float acc = b;
        for (int k = 0; k < 256; k++)
            acc += sc[n * 256 + k] * ada_w[(long)k * 1536 + j];
        ada[n * 1536 + j] = acc;
    }
}

// ---------------- fused LayerNorm + modulate -> bf16 -----------------------
__global__ __launch_bounds__(256) void ln_mod(const float* __restrict__ x,
                                              const float* __restrict__ ada,
                                              int off_sh, int off_sc,
                                              __hip_bfloat16* __restrict__ out) {
    int row = blockIdx.x * 4 + (threadIdx.x >> 6);
    int lane = threadIdx.x & 63;
    const float4 v = *(const float4*)&x[(long)row * 256 + lane * 4];
    float s = v.x + v.y + v.z + v.w;
    float s2 = v.x * v.x + v.y * v.y + v.z * v.z + v.w * v.w;
#pragma unroll
    for (int o = 32; o > 0; o >>= 1) {
        s += __shfl_xor(s, o, 64);
        s2 += __shfl_xor(s2, o, 64);
    }
    float mu = s * (1.0f / 256.0f);
    float var = s2 * (1.0f / 256.0f) - mu * mu;
    float rstd = rsqrtf(var + 1e-6f);
    int nb = row >> 12;
    const float* sh = &ada[nb * 1536 + off_sh];
    const float* scp = &ada[nb * 1536 + off_sc];
    float vv[4] = {v.x, v.y, v.z, v.w};
#pragma unroll
    for (int e = 0; e < 4; e++) {
        int col = lane * 4 + e;
        float val = (vv[e] - mu) * rstd;
        val = val * (1.0f + scp[col]) + sh[col];
        out[(long)row * 256 + col] = __float2bfloat16(val);
    }
}

// ---------------- bf16 MFMA GEMM: C = A(MxK) @ Bt(NxK)^T  + epilogue -------
// m97 structure: global_load_lds width=16, linear LDS, 2-barrier K-loop.
// MODE 0: qkv   -> outb = acc + bias                        (bf16)
// MODE 1: proj  -> outf = resid + g_msa * (acc + bias)      (f32, d_out)
// MODE 2: fc1   -> outb = gelu_tanh(acc + bias)             (bf16)
// MODE 3: fc2   -> outf = outf + g_mlp * (acc + bias)       (f32, d_out in/out)
template <int MODE>
__global__ __launch_bounds__(256) void gemm_bt(const __hip_bfloat16* __restrict__ A,
                                               const __hip_bfloat16* __restrict__ Bt,
                                               const float* __restrict__ bias,
                                               const float* __restrict__ resid,
                                               const float* __restrict__ ada,
                                               float* __restrict__ outf,
                                               __hip_bfloat16* __restrict__ outb,
                                               int M, int N, int K) {
    __shared__ u16 As[128 * 64];   // linear: global_load_lds needs contiguous dest
    __shared__ u16 Bs[128 * 64];
    int tid = threadIdx.x;
    int lane = tid & 63;
    int wid = tid >> 6;
    int wr = wid >> 1, wc = wid & 1;
    int brow = blockIdx.y * 128;
    int bcol = blockIdx.x * 128;
    int la = lane & 15, lb = lane >> 4;

    f32x4 acc[4][4] = {};

    const u16* Ag = (const u16*)A;
    const u16* Bg = (const u16*)Bt;

    for (int k0 = 0; k0 < K; k0 += 64) {
        __syncthreads();   // previous compute done before LDS overwrite
#pragma unroll
        for (int i = 0; i < 4; i++) {
            int c = (wid * 4 + i) * 64 + lane;   // 16B chunk id, 0..1023
            int row = c >> 3;
            int col = (c & 7) << 3;
            __builtin_amdgcn_global_load_lds(
                (const g_void*)(Ag + (long)(brow + row) * K + k0 + col),
                (lds_void*)&As[(wid * 4 + i) * 512], 16, 0, 0);
            __builtin_amdgcn_global_load_lds(
                (const g_void*)(Bg + (long)(bcol + row) * K + k0 + col),
                (lds_void*)&Bs[(wid * 4 + i) * 512], 16, 0, 0);
        }
        __syncthreads();   // drains vmcnt(0): tiles ready
#pragma unroll
        for (int kk = 0; kk < 64; kk += 32) {
            s16x8 af[4], bfr[4];
#pragma unroll
            for (int m = 0; m < 4; m++)
                af[m] = *(const s16x8*)&As[(wr * 64 + m * 16 + la) * 64 + kk + lb * 8];
#pragma unroll
            for (int n2 = 0; n2 < 4; n2++)
                bfr[n2] = *(const s16x8*)&Bs[(wc * 64 + n2 * 16 + la) * 64 + kk + lb * 8];
#pragma unroll
            for (int m = 0; m < 4; m++)
#pragma unroll
                for (int n2 = 0; n2 < 4; n2++)
                    acc[m][n2] = __builtin_amdgcn_mfma_f32_16x16x32_bf16(
                        af[m], bfr[n2], acc[m][n2], 0, 0, 0);
        }
    }

    int nb = brow >> 12;  // batch index (4096 rows/batch, 128 | 4096)
#pragma unroll
    for (int m = 0; m < 4; m++) {
#pragma unroll
        for (int n2 = 0; n2 < 4; n2++) {
#pragma unroll
            for (int r = 0; r < 4; r++) {
                int row = brow + wr * 64 + m * 16 + lb * 4 + r;
                int col = bcol + wc * 64 + n2 * 16 + la;
                float v = acc[m][n2][r] + bias[col];
                long oidx = (long)row * N + col;
                if (MODE == 0) {
                    outb[oidx] = __float2bfloat16(v);
                } else if (MODE == 1) {
                    float g = ada[nb * 1536 + 512 + col];
                    outf[oidx] = resid[oidx] + g * v;
                } else if (MODE == 2) {
                    float t = tanhf(0.7978845608028654f * (v + 0.044715f * v * v * v));
                    outb[oidx] = __float2bfloat16(0.5f * v * (1.0f + t));
                } else {
                    float g = ada[nb * 1536 + 1280 + col];
                    outf[oidx] = outf[oidx] + g * v;
                }
            }
        }
    }
}

// ---------------- MFMA window attention ------------------------------------
// Block = 4 waves, all same head h (shared bias LDS); wave w owns one window.
// Per wave: S(64x64) = Q Kt : 16 MFMA;  O = P V : 16 MFMA.
// C-layout (16x16x32): col = lane&15, row = (lane>>4)*4 + r.
__global__ __launch_bounds__(256) void win_attn_mfma(const __hip_bfloat16* __restrict__ qkv,
                                                     const float* __restrict__ rpb,
                                                     __hip_bfloat16* __restrict__ out) {
    __shared__ float bias_s[64 * 64];   // 16 KB, shared (one head per block)
    __shared__ u16 vt[4][32 * 72];      // per-wave V^T, pad 72
    __shared__ u16 pl[4][64 * 72];      // per-wave P, pad 72

    int tid = threadIdx.x;
    int bid = blockIdx.x;
    int h = bid & 7;
    int w = tid >> 6;
    int lane = tid & 63;
    int la = lane & 15, lb = lane >> 4;
    int win = (bid >> 3) * 4 + w;
    int n = win >> 6;
    int wh = (win >> 3) & 7;
    int ww = win & 7;
    long base_row = (long)n * 4096 + (long)(wh * 8) * 64 + ww * 8;

    // bias table for this head
    for (int i = tid; i < 4096; i += 256) {
        int t = i >> 6, j = i & 63;
        int idx = ((t >> 3) - (j >> 3) + 7) * 15 + ((t & 7) - (j & 7) + 7);
        bias_s[i] = rpb[idx * 8 + h];
    }

    const u16* qg = (const u16*)qkv;

    // Q/K fragments (A: row=la, kchunk=lb*8 ; B: col=la, kchunk=lb*8)
    s16x8 qf[4], kf[4];
#pragma unroll
    for (int rt = 0; rt < 4; rt++) {
        int t = rt * 16 + la;
        long sr = base_row + (t >> 3) * 64 + (t & 7);
        qf[rt] = *(const s16x8*)(qg + sr * 768 + h * 32 + lb * 8);
        kf[rt] = *(const s16x8*)(qg + sr * 768 + 256 + h * 32 + lb * 8);
    }
    // stage V^T into LDS: vt[d][t]
#pragma unroll
    for (int g = 0; g < 4; g++) {
        int t = g * 16 + la;
        long sr = base_row + (t >> 3) * 64 + (t & 7);
        u16x8 vv = *(const u16x8*)(qg + sr * 768 + 512 + h * 32 + lb * 8);
#pragma unroll
        for (int e = 0; e < 8; e++) vt[w][(lb * 8 + e) * 72 + t] = vv[e];
    }

    // S = Q K^T
    f32x4 sa[4][4];
    f32x4 zero = {};
#pragma unroll
    for (int rt = 0; rt < 4; rt++)
#pragma unroll
        for (int ct = 0; ct < 4; ct++)
            sa[rt][ct] = __builtin_amdgcn_mfma_f32_16x16x32_bf16(qf[rt], kf[ct], zero, 0, 0, 0);

    __syncthreads();   // bias_s + vt ready

    // softmax (rows: t = rt*16 + lb*4 + r; keys: j = ct*16 + la)
    float rls[4][4];
#pragma unroll
    for (int rt = 0; rt < 4; rt++) {
#pragma unroll
        for (int r = 0; r < 4; r++) {
            int t = rt * 16 + lb * 4 + r;
            float v0 = sa[rt][0][r] * 0.17677669529663687f + bias_s[t * 64 + 0 * 16 + la];
            float v1 = sa[rt][1][r] * 0.17677669529663687f + bias_s[t * 64 + 1 * 16 + la];
            float v2 = sa[rt][2][r] * 0.17677669529663687f + bias_s[t * 64 + 2 * 16 + la];
            float v3 = sa[rt][3][r] * 0.17677669529663687f + bias_s[t * 64 + 3 * 16 + la];
            float mx = fmaxf(fmaxf(v0, v1), fmaxf(v2, v3));
#pragma unroll
            for (int o = 1; o < 16; o <<= 1) mx = fmaxf(mx, __shfl_xor(mx, o, 64));
            float p0 = __expf(v0 - mx), p1 = __expf(v1 - mx);
            float p2 = __expf(v2 - mx), p3 = __expf(v3 - mx);
            float sum = (p0 + p1) + (p2 + p3);
#pragma unroll
            for (int o = 1; o < 16; o <<= 1) sum += __shfl_xor(sum, o, 64);
            sa[rt][0][r] = p0; sa[rt][1][r] = p1; sa[rt][2][r] = p2; sa[rt][3][r] = p3;
            rls[rt][r] = 1.0f / sum;
        }
    }

    // P -> LDS (bf16), layout pl[t][j]
#pragma unroll
    for (int rt = 0; rt < 4; rt++)
#pragma unroll
        for (int ct = 0; ct < 4; ct++)
#pragma unroll
            for (int r = 0; r < 4; r++)
                pl[w][(rt * 16 + lb * 4 + r) * 72 + ct * 16 + la] = f2bf(sa[rt][ct][r]);

    __syncthreads();   // pl/vt writes drained

    // O = P V
    f32x4 oa[4][2] = {};
#pragma unroll
    for (int ks = 0; ks < 2; ks++) {
        s16x8 vf[2];
#pragma unroll
        for (int dt = 0; dt < 2; dt++)
            vf[dt] = *(const s16x8*)&vt[w][(dt * 16 + la) * 72 + ks * 32 + lb * 8];
#pragma unroll
        for (int rt = 0; rt < 4; rt++) {
            s16x8 pf = *(const s16x8*)&pl[w][(rt * 16 + la) * 72 + ks * 32 + lb * 8];
#pragma unroll
            for (int dt = 0; dt < 2; dt++)
                oa[rt][dt] = __builtin_amdgcn_mfma_f32_16x16x32_bf16(pf, vf[dt], oa[rt][dt], 0, 0, 0);
        }
    }

    // write O (normalize by 1/lsum here; lane row mapping matches S)
#pragma unroll
    for (int rt = 0; rt < 4; rt++) {
#pragma unroll
        for (int r = 0; r < 4; r++) {
            int t = rt * 16 + lb * 4 + r;
            long sr = base_row + (t >> 3) * 64 + (t & 7);
#pragma unroll
            for (int dt = 0; dt < 2; dt++) {
                int d = dt * 16 + la;
                out[sr * 256 + h * 32 + d] = __float2bfloat16(oa[rt][dt][r] * rls[rt][r]);
            }
        }
    }
}

// ---------------------------------------------------------------------------
extern "C" void kernel_launch(void* const* d_in, const int* in_sizes, int n_in,
                              void* d_out, int out_size, void* d_ws, size_t ws_size,
                              hipStream_t stream) {
    const float* x_seq  = (const float*)d_in[0];
    const float* c      = (const float*)d_in[1];
    const float* qkv_w  = (const float*)d_in[2];
    const float* qkv_b  = (const float*)d_in[3];
    const float* proj_w = (const float*)d_in[4];
    const float* proj_b = (const float*)d_in[5];
    const float* rpb    = (const float*)d_in[6];
    const float* ada_w  = (const float*)d_in[7];
    const float* ada_b  = (const float*)d_in[8];
    const float* fc1_w  = (const float*)d_in[9];
    const float* fc1_b  = (const float*)d_in[10];
    const float* fc2_w  = (const float*)d_in[11];
    const float* fc2_b  = (const float*)d_in[12];

    char* ws = (char*)d_ws;
    float* ada             = (float*)ws;                       // 96 KB
    __hip_bfloat16* qkv_wt = (__hip_bfloat16*)(ws + 131072);   // 768x256 bf16
    __hip_bfloat16* proj_wt= (__hip_bfloat16*)(ws + 524288);   // 256x256
    __hip_bfloat16* fc1_wt = (__hip_bfloat16*)(ws + 655360);   // 1024x256
    __hip_bfloat16* fc2_wt = (__hip_bfloat16*)(ws + 1179648);  // 256x1024
    __hip_bfloat16* bufA   = (__hip_bfloat16*)(ws + 2097152);  // 32 MB: xb / attn_out / xmlp
    __hip_bfloat16* bufB   = (__hip_bfloat16*)(ws + 35651584); // 128 MB: qkv / h1
    float* outf = (float*)d_out;

    wconv_t<<<(256 * 768 + 255) / 256, 256, 0, stream>>>(qkv_w, qkv_wt, 256, 768);
    wconv_t<<<(256 * 256 + 255) / 256, 256, 0, stream>>>(proj_w, proj_wt, 256, 256);
    wconv_t<<<(256 * 1024 + 255) / 256, 256, 0, stream>>>(fc1_w, fc1_wt, 256, 1024);
    wconv_t<<<(1024 * 256 + 255) / 256, 256, 0, stream>>>(fc2_w, fc2_wt, 1024, 256);

    ada_kernel<<<6, 256, 0, stream>>>(c, ada_w, ada_b, ada);

    // x_win LN+modulate (MSA) -> bufA (bf16)
    ln_mod<<<TTOT / 4, 256, 0, stream>>>(x_seq, ada, 0, 256, bufA);

    // qkv = bufA @ qkv_w + b -> bufB (bf16, 65536 x 768)
    {
        dim3 g(768 / 128, TTOT / 128);
        gemm_bt<0><<<g, 256, 0, stream>>>(bufA, qkv_wt, qkv_b, nullptr, ada,
                                          nullptr, bufB, TTOT, 768, 256);
    }
    // window attention -> bufA (bf16, 65536 x 256)
    win_attn_mfma<<<2048, 256, 0, stream>>>(bufB, rpb, bufA);

    // out1 = x_seq + g_msa * (attn @ proj_w + b) -> d_out (f32)
    {
        dim3 g(256 / 128, TTOT / 128);
        gemm_bt<1><<<g, 256, 0, stream>>>(bufA, proj_wt, proj_b, x_seq, ada,
                                          outf, nullptr, TTOT, 256, 256);
    }
    // LN+modulate (MLP) -> bufA (bf16)
    ln_mod<<<TTOT / 4, 256, 0, stream>>>(outf, ada, 768, 1024, bufA);

    // h1 = gelu(bufA @ fc1_w + b) -> bufB (bf16, 65536 x 1024)
    {
        dim3 g(1024 / 128, TTOT / 128);
        gemm_bt<2><<<g, 256, 0, stream>>>(bufA, fc1_wt, fc1_b, nullptr, ada,
                                          nullptr, bufB, TTOT, 1024, 256);
    }
    // out = out1 + g_mlp * (h1 @ fc2_w + b) -> d_out (f32)
    {
        dim3 g(256 / 128, TTOT / 128);
        gemm_bt<3><<<g, 256, 0, stream>>>(bufB, fc2_wt, fc2_b, nullptr, ada,
                                          outf, nullptr, TTOT, 256, 1024);
    }
}

// Round 4
// 441.220 us; speedup vs baseline: 1.3273x; 1.1116x over previous
//
#include <hip/hip_runtime.h>
#include <hip/hip_bf16.h>

#define TTOT 65536  // 16 * 4096 rows

using f32x4 = __attribute__((ext_vector_type(4))) float;
using s16x8 = __attribute__((ext_vector_type(8))) short;
typedef unsigned short u16;
using u16x8 = __attribute__((ext_vector_type(8))) u16;

typedef __attribute__((address_space(3))) void lds_void;
typedef __attribute__((address_space(1))) void g_void;

__device__ __forceinline__ float bf2f(u16 u) {
    union { unsigned int ui; float f; } v; v.ui = ((unsigned int)u) << 16; return v.f;
}

__device__ __forceinline__ u16 f2bf(float f) {
    return __bfloat16_as_ushort(__float2bfloat16(f));
}

// ---------------- weight transpose + bf16 convert: wt[n*K+k] = w[k*N+n] ----
__global__ void wconv_t(const float* __restrict__ w, __hip_bfloat16* __restrict__ wt,
                        int K, int N) {
    int idx = blockIdx.x * 256 + threadIdx.x;
    if (idx >= K * N) return;
    int n = idx / K, k = idx - n * K;
    wt[idx] = __float2bfloat16(w[(long)k * N + n]);
}

// ---------------- ada = silu(c) @ ada_w + ada_b   (16 x 1536) --------------
__global__ __launch_bounds__(256) void ada_kernel(const float* __restrict__ c,
                                                  const float* __restrict__ ada_w,
                                                  const float* __restrict__ ada_b,
                                                  float* __restrict__ ada) {
    __shared__ float sc[16 * 256];
    int tid = threadIdx.x;
    for (int i = tid; i < 16 * 256; i += 256) {
        float v = c[i];
        sc[i] = v / (1.0f + expf(-v));
    }
    __syncthreads();
    int j = blockIdx.x * 256 + tid;   // grid = 6 -> j in [0,1536)
    float b = ada_b[j];
    for (int n = 0; n < 16; n++) {
        float acc = b;
        for (int k = 0; k < 256; k++)
            acc += sc[n * 256 + k] * ada_w[(long)k * 1536 + j];
        ada[n * 1536 + j] = acc;
    }
}

// ---------------- fused LayerNorm + modulate -> bf16 -----------------------
__global__ __launch_bounds__(256) void ln_mod(const float* __restrict__ x,
                                              const float* __restrict__ ada,
                                              int off_sh, int off_sc,
                                              __hip_bfloat16* __restrict__ out) {
    int row = blockIdx.x * 4 + (threadIdx.x >> 6);
    int lane = threadIdx.x & 63;
    const float4 v = *(const float4*)&x[(long)row * 256 + lane * 4];
    float s = v.x + v.y + v.z + v.w;
    float s2 = v.x * v.x + v.y * v.y + v.z * v.z + v.w * v.w;
#pragma unroll
    for (int o = 32; o > 0; o >>= 1) {
        s += __shfl_xor(s, o, 64);
        s2 += __shfl_xor(s2, o, 64);
    }
    float mu = s * (1.0f / 256.0f);
    float var = s2 * (1.0f / 256.0f) - mu * mu;
    float rstd = rsqrtf(var + 1e-6f);
    int nb = row >> 12;
    const float* sh = &ada[nb * 1536 + off_sh];
    const float* scp = &ada[nb * 1536 + off_sc];
    float vv[4] = {v.x, v.y, v.z, v.w};
#pragma unroll
    for (int e = 0; e < 4; e++) {
        int col = lane * 4 + e;
        float val = (vv[e] - mu) * rstd;
        val = val * (1.0f + scp[col]) + sh[col];
        out[(long)row * 256 + col] = __float2bfloat16(val);
    }
}

// ---------------- bf16 MFMA GEMM: C = A(MxK) @ Bt(NxK)^T  + epilogue -------
// 2-phase dbuf pipeline (counted vmcnt), XOR-swizzled LDS (both-sides, rule 21).
// MODE 0: qkv   -> outb = acc + bias                        (bf16)
// MODE 1: proj  -> outf = resid + g_msa * (acc + bias)      (f32, d_out)
// MODE 2: fc1   -> outb = gelu(acc + bias) = v*sigmoid(2u)  (bf16)
// MODE 3: fc2   -> outf = outf + g_mlp * (acc + bias)       (f32, d_out in/out)
template <int MODE>
__global__ __launch_bounds__(256) void gemm_bt(const __hip_bfloat16* __restrict__ A,
                                               const __hip_bfloat16* __restrict__ Bt,
                                               const float* __restrict__ bias,
                                               const float* __restrict__ resid,
                                               const float* __restrict__ ada,
                                               float* __restrict__ outf,
                                               __hip_bfloat16* __restrict__ outb,
                                               int M, int N, int K) {
    __shared__ u16 As[2][128 * 64];   // linear dest (global_load_lds), swizzled content
    __shared__ u16 Bs[2][128 * 64];
    int tid = threadIdx.x;
    int lane = tid & 63;
    int wid = tid >> 6;
    int wr = wid >> 1, wc = wid & 1;
    int brow = blockIdx.y * 128;
    int bcol = blockIdx.x * 128;
    int la = lane & 15, lb = lane >> 4;

    f32x4 acc[4][4] = {};

    const u16* Ag = (const u16*)A;
    const u16* Bg = (const u16*)Bt;

    // stage K-step k0 into buffer buf. LDS dest linear; global source chunk
    // pre-swizzled by (row&7) so that a swizzled READ returns correct data.
    auto STAGE = [&](int k0, int buf) {
#pragma unroll
        for (int i = 0; i < 4; i++) {
            int c = (wid * 4 + i) * 64 + lane;   // 16B chunk id, 0..1023
            int row = c >> 3;
            int sc = (c & 7) ^ (row & 7);        // inverse-swizzled source chunk
            __builtin_amdgcn_global_load_lds(
                (const g_void*)(Ag + (long)(brow + row) * K + k0 + sc * 8),
                (lds_void*)&As[buf][(wid * 4 + i) * 512], 16, 0, 0);
            __builtin_amdgcn_global_load_lds(
                (const g_void*)(Bg + (long)(bcol + row) * K + k0 + sc * 8),
                (lds_void*)&Bs[buf][(wid * 4 + i) * 512], 16, 0, 0);
        }
    };

    int NT = K >> 6;
    STAGE(0, 0);
    for (int t = 0; t < NT; ++t) {
        int cur = t & 1;
        if (t + 1 < NT) {
            STAGE((t + 1) << 6, cur ^ 1);
            asm volatile("s_waitcnt vmcnt(8)" ::: "memory");   // tile t landed
        } else {
            asm volatile("s_waitcnt vmcnt(0)" ::: "memory");
        }
        __builtin_amdgcn_s_barrier();   // tile t visible to all waves
#pragma unroll
        for (int kk8 = 0; kk8 < 8; kk8 += 4) {   // kk = kk8*8 in {0,32}
            s16x8 af[4], bfr[4];
#pragma unroll
            for (int m = 0; m < 4; m++) {
                int R = wr * 64 + m * 16 + la;
                af[m] = *(const s16x8*)&As[cur][R * 64 + (((kk8 + lb) ^ (R & 7)) << 3)];
            }
#pragma unroll
            for (int n2 = 0; n2 < 4; n2++) {
                int R = wc * 64 + n2 * 16 + la;
                bfr[n2] = *(const s16x8*)&Bs[cur][R * 64 + (((kk8 + lb) ^ (R & 7)) << 3)];
            }
#pragma unroll
            for (int m = 0; m < 4; m++)
#pragma unroll
                for (int n2 = 0; n2 < 4; n2++)
                    acc[m][n2] = __builtin_amdgcn_mfma_f32_16x16x32_bf16(
                        af[m], bfr[n2], acc[m][n2], 0, 0, 0);
        }
        __builtin_amdgcn_s_barrier();   // reads done before buffer reuse
    }

    int nb = brow >> 12;  // batch index (4096 rows/batch, 128 | 4096)
#pragma unroll
    for (int m = 0; m < 4; m++) {
#pragma unroll
        for (int n2 = 0; n2 < 4; n2++) {
#pragma unroll
            for (int r = 0; r < 4; r++) {
                int row = brow + wr * 64 + m * 16 + lb * 4 + r;
                int col = bcol + wc * 64 + n2 * 16 + la;
                float v = acc[m][n2][r] + bias[col];
                long oidx = (long)row * N + col;
                if (MODE == 0) {
                    outb[oidx] = __float2bfloat16(v);
                } else if (MODE == 1) {
                    float g = ada[nb * 1536 + 512 + col];
                    outf[oidx] = resid[oidx] + g * v;
                } else if (MODE == 2) {
                    // gelu_tanh(v) == v * sigmoid(2*0.7978845608*(v+0.044715 v^3))
                    float u2 = 1.5957691216057308f * (v + 0.044715f * v * v * v);
                    outb[oidx] = __float2bfloat16(v / (1.0f + __expf(-u2)));
                } else {
                    float g = ada[nb * 1536 + 1280 + col];
                    outf[oidx] = outf[oidx] + g * v;
                }
            }
        }
    }
}

// ---------------- MFMA window attention ------------------------------------
// Block = 4 waves, all same head h (shared bias LDS); wave w owns one window.
// Per wave: S(64x64) = Q Kt : 16 MFMA;  O = P V : 16 MFMA.
// C-layout (16x16x32): col = lane&15, row = (lane>>4)*4 + r.
__global__ __launch_bounds__(256) void win_attn_mfma(const __hip_bfloat16* __restrict__ qkv,
                                                     const float* __restrict__ rpb,
                                                     __hip_bfloat16* __restrict__ out) {
    __shared__ float bias_s[64 * 64];   // 16 KB, shared (one head per block)
    __shared__ u16 vt[4][32 * 72];      // per-wave V^T, pad 72
    __shared__ u16 pl[4][64 * 72];      // per-wave P, pad 72

    int tid = threadIdx.x;
    int bid = blockIdx.x;
    int h = bid & 7;
    int w = tid >> 6;
    int lane = tid & 63;
    int la = lane & 15, lb = lane >> 4;
    int win = (bid >> 3) * 4 + w;
    int n = win >> 6;
    int wh = (win >> 3) & 7;
    int ww = win & 7;
    long base_row = (long)n * 4096 + (long)(wh * 8) * 64 + ww * 8;

    // bias table for this head
    for (int i = tid; i < 4096; i += 256) {
        int t = i >> 6, j = i & 63;
        int idx = ((t >> 3) - (j >> 3) + 7) * 15 + ((t & 7) - (j & 7) + 7);
        bias_s[i] = rpb[idx * 8 + h];
    }

    const u16* qg = (const u16*)qkv;

    // Q/K fragments (A: row=la, kchunk=lb*8 ; B: col=la, kchunk=lb*8)
    s16x8 qf[4], kf[4];
#pragma unroll
    for (int rt = 0; rt < 4; rt++) {
        int t = rt * 16 + la;
        long sr = base_row + (t >> 3) * 64 + (t & 7);
        qf[rt] = *(const s16x8*)(qg + sr * 768 + h * 32 + lb * 8);
        kf[rt] = *(const s16x8*)(qg + sr * 768 + 256 + h * 32 + lb * 8);
    }
    // stage V^T into LDS: vt[d][t]
#pragma unroll
    for (int g = 0; g < 4; g++) {
        int t = g * 16 + la;
        long sr = base_row + (t >> 3) * 64 + (t & 7);
        u16x8 vv = *(const u16x8*)(qg + sr * 768 + 512 + h * 32 + lb * 8);
#pragma unroll
        for (int e = 0; e < 8; e++) vt[w][(lb * 8 + e) * 72 + t] = vv[e];
    }

    // S = Q K^T
    f32x4 sa[4][4];
    f32x4 zero = {};
#pragma unroll
    for (int rt = 0; rt < 4; rt++)
#pragma unroll
        for (int ct = 0; ct < 4; ct++)
            sa[rt][ct] = __builtin_amdgcn_mfma_f32_16x16x32_bf16(qf[rt], kf[ct], zero, 0, 0, 0);

    __syncthreads();   // bias_s + vt ready

    // softmax (rows: t = rt*16 + lb*4 + r; keys: j = ct*16 + la)
    float rls[4][4];
#pragma unroll
    for (int rt = 0; rt < 4; rt++) {
#pragma unroll
        for (int r = 0; r < 4; r++) {
            int t = rt * 16 + lb * 4 + r;
            float v0 = sa[rt][0][r] * 0.17677669529663687f + bias_s[t * 64 + 0 * 16 + la];
            float v1 = sa[rt][1][r] * 0.17677669529663687f + bias_s[t * 64 + 1 * 16 + la];
            float v2 = sa[rt][2][r] * 0.17677669529663687f + bias_s[t * 64 + 2 * 16 + la];
            float v3 = sa[rt][3][r] * 0.17677669529663687f + bias_s[t * 64 + 3 * 16 + la];
            float mx = fmaxf(fmaxf(v0, v1), fmaxf(v2, v3));
#pragma unroll
            for (int o = 1; o < 16; o <<= 1) mx = fmaxf(mx, __shfl_xor(mx, o, 64));
            float p0 = __expf(v0 - mx), p1 = __expf(v1 - mx);
            float p2 = __expf(v2 - mx), p3 = __expf(v3 - mx);
            float sum = (p0 + p1) + (p2 + p3);
#pragma unroll
            for (int o = 1; o < 16; o <<= 1) sum += __shfl_xor(sum, o, 64);
            sa[rt][0][r] = p0; sa[rt][1][r] = p1; sa[rt][2][r] = p2; sa[rt][3][r] = p3;
            rls[rt][r] = 1.0f / sum;
        }
    }

    // P -> LDS (bf16), layout pl[t][j]
#pragma unroll
    for (int rt = 0; rt < 4; rt++)
#pragma unroll
        for (int ct = 0; ct < 4; ct++)
#pragma unroll
            for (int r = 0; r < 4; r++)
                pl[w][(rt * 16 + lb * 4 + r) * 72 + ct * 16 + la] = f2bf(sa[rt][ct][r]);

    __syncthreads();   // pl/vt writes drained

    // O = P V
    f32x4 oa[4][2] = {};
#pragma unroll
    for (int ks = 0; ks < 2; ks++) {
        s16x8 vf[2];
#pragma unroll
        for (int dt = 0; dt < 2; dt++)
            vf[dt] = *(const s16x8*)&vt[w][(dt * 16 + la) * 72 + ks * 32 + lb * 8];
#pragma unroll
        for (int rt = 0; rt < 4; rt++) {
            s16x8 pf = *(const s16x8*)&pl[w][(rt * 16 + la) * 72 + ks * 32 + lb * 8];
#pragma unroll
            for (int dt = 0; dt < 2; dt++)
                oa[rt][dt] = __builtin_amdgcn_mfma_f32_16x16x32_bf16(pf, vf[dt], oa[rt][dt], 0, 0, 0);
        }
    }

    // write O (normalize by 1/lsum here; lane row mapping matches S)
#pragma unroll
    for (int rt = 0; rt < 4; rt++) {
#pragma unroll
        for (int r = 0; r < 4; r++) {
            int t = rt * 16 + lb * 4 + r;
            long sr = base_row + (t >> 3) * 64 + (t & 7);
#pragma unroll
            for (int dt = 0; dt < 2; dt++) {
                int d = dt * 16 + la;
                out[sr * 256 + h * 32 + d] = __float2bfloat16(oa[rt][dt][r] * rls[rt][r]);
            }
        }
    }
}

// ---------------------------------------------------------------------------
extern "C" void kernel_launch(void* const* d_in, const int* in_sizes, int n_in,
                              void* d_out, int out_size, void* d_ws, size_t ws_size,
                              hipStream_t stream) {
    const float* x_seq  = (const float*)d_in[0];
    const float* c      = (const float*)d_in[1];
    const float* qkv_w  = (const float*)d_in[2];
    const float* qkv_b  = (const float*)d_in[3];
    const float* proj_w = (const float*)d_in[4];
    const float* proj_b = (const float*)d_in[5];
    const float* rpb    = (const float*)d_in[6];
    const float* ada_w  = (const float*)d_in[7];
    const float* ada_b  = (const float*)d_in[8];
    const float* fc1_w  = (const float*)d_in[9];
    const float* fc1_b  = (const float*)d_in[10];
    const float* fc2_w  = (const float*)d_in[11];
    const float* fc2_b  = (const float*)d_in[12];

    char* ws = (char*)d_ws;
    float* ada             = (float*)ws;                       // 96 KB
    __hip_bfloat16* qkv_wt = (__hip_bfloat16*)(ws + 131072);   // 768x256 bf16
    __hip_bfloat16* proj_wt= (__hip_bfloat16*)(ws + 524288);   // 256x256
    __hip_bfloat16* fc1_wt = (__hip_bfloat16*)(ws + 655360);   // 1024x256
    __hip_bfloat16* fc2_wt = (__hip_bfloat16*)(ws + 1179648);  // 256x1024
    __hip_bfloat16* bufA   = (__hip_bfloat16*)(ws + 2097152);  // 32 MB: xb / attn_out / xmlp
    __hip_bfloat16* bufB   = (__hip_bfloat16*)(ws + 35651584); // 128 MB: qkv / h1
    float* outf = (float*)d_out;

    wconv_t<<<(256 * 768 + 255) / 256, 256, 0, stream>>>(qkv_w, qkv_wt, 256, 768);
    wconv_t<<<(256 * 256 + 255) / 256, 256, 0, stream>>>(proj_w, proj_wt, 256, 256);
    wconv_t<<<(256 * 1024 + 255) / 256, 256, 0, stream>>>(fc1_w, fc1_wt, 256, 1024);
    wconv_t<<<(1024 * 256 + 255) / 256, 256, 0, stream>>>(fc2_w, fc2_wt, 1024, 256);

    ada_kernel<<<6, 256, 0, stream>>>(c, ada_w, ada_b, ada);

    // x_win LN+modulate (MSA) -> bufA (bf16)
    ln_mod<<<TTOT / 4, 256, 0, stream>>>(x_seq, ada, 0, 256, bufA);

    // qkv = bufA @ qkv_w + b -> bufB (bf16, 65536 x 768)
    {
        dim3 g(768 / 128, TTOT / 128);
        gemm_bt<0><<<g, 256, 0, stream>>>(bufA, qkv_wt, qkv_b, nullptr, ada,
                                          nullptr, bufB, TTOT, 768, 256);
    }
    // window attention -> bufA (bf16, 65536 x 256)
    win_attn_mfma<<<2048, 256, 0, stream>>>(bufB, rpb, bufA);

    // out1 = x_seq + g_msa * (attn @ proj_w + b) -> d_out (f32)
    {
        dim3 g(256 / 128, TTOT / 128);
        gemm_bt<1><<<g, 256, 0, stream>>>(bufA, proj_wt, proj_b, x_seq, ada,
                                          outf, nullptr, TTOT, 256, 256);
    }
    // LN+modulate (MLP) -> bufA (bf16)
    ln_mod<<<TTOT / 4, 256, 0, stream>>>(outf, ada, 768, 1024, bufA);

    // h1 = gelu(bufA @ fc1_w + b) -> bufB (bf16, 65536 x 1024)
    {
        dim3 g(1024 / 128, TTOT / 128);
        gemm_bt<2><<<g, 256, 0, stream>>>(bufA, fc1_wt, fc1_b, nullptr, ada,
                                          nullptr, bufB, TTOT, 1024, 256);
    }
    // out = out1 + g_mlp * (h1 @ fc2_w + b) -> d_out (f32)
    {
        dim3 g(256 / 128, TTOT / 128);
        gemm_bt<3><<<g, 256, 0, stream>>>(bufB, fc2_wt, fc2_b, nullptr, ada,
                                          outf, nullptr, TTOT, 256, 1024);
    }
}

// Round 5
// 430.426 us; speedup vs baseline: 1.3606x; 1.0251x over previous
//
#include <hip/hip_runtime.h>
#include <hip/hip_bf16.h>

#define TTOT 65536  // 16 * 4096 rows

using f32x4 = __attribute__((ext_vector_type(4))) float;
using s16x8 = __attribute__((ext_vector_type(8))) short;
typedef unsigned short u16;
using u16x8 = __attribute__((ext_vector_type(8))) u16;

typedef __attribute__((address_space(3))) void lds_void;
typedef __attribute__((address_space(1))) void g_void;

__device__ __forceinline__ float bf2f(u16 u) {
    union { unsigned int ui; float f; } v; v.ui = ((unsigned int)u) << 16; return v.f;
}

__device__ __forceinline__ u16 f2bf(float f) {
    return __bfloat16_as_ushort(__float2bfloat16(f));
}

// ---------------- weight transpose + bf16 convert: wt[n*K+k] = w[k*N+n] ----
__global__ void wconv_t(const float* __restrict__ w, __hip_bfloat16* __restrict__ wt,
                        int K, int N) {
    int idx = blockIdx.x * 256 + threadIdx.x;
    if (idx >= K * N) return;
    int n = idx / K, k = idx - n * K;
    wt[idx] = __float2bfloat16(w[(long)k * N + n]);
}

// ---------------- ada = silu(c) @ ada_w + ada_b   (16 x 1536) --------------
__global__ __launch_bounds__(256) void ada_kernel(const float* __restrict__ c,
                                                  const float* __restrict__ ada_w,
                                                  const float* __restrict__ ada_b,
                                                  float* __restrict__ ada) {
    __shared__ float sc[16 * 256];
    int tid = threadIdx.x;
    for (int i = tid; i < 16 * 256; i += 256) {
        float v = c[i];
        sc[i] = v / (1.0f + expf(-v));
    }
    __syncthreads();
    int j = blockIdx.x * 256 + tid;   // grid = 6 -> j in [0,1536)
    float b = ada_b[j];
    for (int n = 0; n < 16; n++) {
        float acc = b;
        for (int k = 0; k < 256; k++)
            acc += sc[n * 256 + k] * ada_w[(long)k * 1536 + j];
        ada[n * 1536 + j] = acc;
    }
}

// ---------------- fused LayerNorm + modulate -> bf16 -----------------------
__global__ __launch_bounds__(256) void ln_mod(const float* __restrict__ x,
                                              const float* __restrict__ ada,
                                              int off_sh, int off_sc,
                                              __hip_bfloat16* __restrict__ out) {
    int row = blockIdx.x * 4 + (threadIdx.x >> 6);
    int lane = threadIdx.x & 63;
    const float4 v = *(const float4*)&x[(long)row * 256 + lane * 4];
    float s = v.x + v.y + v.z + v.w;
    float s2 = v.x * v.x + v.y * v.y + v.z * v.z + v.w * v.w;
#pragma unroll
    for (int o = 32; o > 0; o >>= 1) {
        s += __shfl_xor(s, o, 64);
        s2 += __shfl_xor(s2, o, 64);
    }
    float mu = s * (1.0f / 256.0f);
    float var = s2 * (1.0f / 256.0f) - mu * mu;
    float rstd = rsqrtf(var + 1e-6f);
    int nb = row >> 12;
    const float* sh = &ada[nb * 1536 + off_sh];
    const float* scp = &ada[nb * 1536 + off_sc];
    float vv[4] = {v.x, v.y, v.z, v.w};
#pragma unroll
    for (int e = 0; e < 4; e++) {
        int col = lane * 4 + e;
        float val = (vv[e] - mu) * rstd;
        val = val * (1.0f + scp[col]) + sh[col];
        out[(long)row * 256 + col] = __float2bfloat16(val);
    }
}

// ---------------- bf16 MFMA GEMM, 256x256 tile, 8 waves --------------------
// T2 XOR-swizzled LDS (measured 0 conflicts), T4 counted vmcnt(8) burst
// prefetch, T5 setprio, T1 XCD-locality block remap (each XCD owns a
// contiguous M-chunk and sweeps N fastest -> A panel fetched by ONE XCD).
// MODE 0: qkv   -> outb = acc + bias                        (bf16)
// MODE 1: proj  -> outf = resid + g_msa * (acc + bias)      (f32, d_out)
// MODE 2: fc1   -> outb = gelu(acc + bias) = v*sigmoid(2u)  (bf16)
// MODE 3: fc2   -> outf = outf + g_mlp * (acc + bias)       (f32, d_out in/out)
template <int MODE>
__global__ __launch_bounds__(512) void gemm_bt(const __hip_bfloat16* __restrict__ A,
                                               const __hip_bfloat16* __restrict__ Bt,
                                               const float* __restrict__ bias,
                                               const float* __restrict__ resid,
                                               const float* __restrict__ ada,
                                               float* __restrict__ outf,
                                               __hip_bfloat16* __restrict__ outb,
                                               int M, int N, int K, int NX) {
    __shared__ u16 As[2][256 * 64];   // 64 KB (linear dest, swizzled content)
    __shared__ u16 Bs[2][256 * 64];   // 64 KB
    int tid = threadIdx.x;
    int lane = tid & 63;
    int wid = tid >> 6;                 // 0..7
    int wr = wid >> 2, wc = wid & 3;    // 2 (M) x 4 (N) wave grid
    int la = lane & 15, lb = lane >> 4;

    // XCD-locality remap: NY = M/256 (=256), YPX = NY/8 (=32).
    int bid = blockIdx.x;
    int xcd = bid & 7;
    int t0 = bid >> 3;
    int x = t0 % NX;
    int yin = t0 / NX;
    int YPX = (int)(gridDim.x >> 3) / NX;
    int y = xcd * YPX + yin;
    int brow = y * 256;
    int bcol = x * 256;

    f32x4 acc[8][4] = {};

    const u16* Ag = (const u16*)A;
    const u16* Bg = (const u16*)Bt;

    // stage K-tile k0 into buffer buf: 4 A-loads + 4 B-loads per thread.
    // LDS dest linear; global source column-chunk pre-swizzled by (row&7).
    auto STAGE = [&](int k0, int buf) {
#pragma unroll
        for (int i = 0; i < 4; i++) {
            int c = i * 512 + tid;            // 16B chunk id, 0..2047
            int row = c >> 3;
            int sc = (c & 7) ^ (row & 7);     // inverse-swizzled source chunk
            __builtin_amdgcn_global_load_lds(
                (const g_void*)(Ag + (long)(brow + row) * K + k0 + sc * 8),
                (lds_void*)&As[buf][(i * 512 + wid * 64) * 8], 16, 0, 0);
            __builtin_amdgcn_global_load_lds(
                (const g_void*)(Bg + (long)(bcol + row) * K + k0 + sc * 8),
                (lds_void*)&Bs[buf][(i * 512 + wid * 64) * 8], 16, 0, 0);
        }
    };

    int NT = K >> 6;
    STAGE(0, 0);
    for (int t = 0; t < NT; ++t) {
        int cur = t & 1;
        if (t + 1 < NT) {
            STAGE((t + 1) << 6, cur ^ 1);                    // burst prefetch
            asm volatile("s_waitcnt vmcnt(8)" ::: "memory"); // tile t landed
        } else {
            asm volatile("s_waitcnt vmcnt(0)" ::: "memory");
        }
        __builtin_amdgcn_s_barrier();   // tile t visible to all waves
#pragma unroll
        for (int kk = 0; kk < 2; kk++) {   // phase = K-half (32 each)
            s16x8 af[8], bfr[4];
#pragma unroll
            for (int n2 = 0; n2 < 4; n2++) {
                int R = wc * 64 + n2 * 16 + la;
                bfr[n2] = *(const s16x8*)&Bs[cur][R * 64 + (((kk * 4 + lb) ^ (R & 7)) << 3)];
            }
#pragma unroll
            for (int m = 0; m < 8; m++) {
                int R = wr * 128 + m * 16 + la;
                af[m] = *(const s16x8*)&As[cur][R * 64 + (((kk * 4 + lb) ^ (R & 7)) << 3)];
            }
            __builtin_amdgcn_s_setprio(1);
#pragma unroll
            for (int m = 0; m < 8; m++)
#pragma unroll
                for (int n2 = 0; n2 < 4; n2++)
                    acc[m][n2] = __builtin_amdgcn_mfma_f32_16x16x32_bf16(
                        af[m], bfr[n2], acc[m][n2], 0, 0, 0);
            __builtin_amdgcn_s_setprio(0);
        }
        __builtin_amdgcn_s_barrier();   // reads done before buffer reuse
    }

    int nb = brow >> 12;  // batch index (4096 rows/batch, 256 | 4096)
#pragma unroll
    for (int m = 0; m < 8; m++) {
#pragma unroll
        for (int n2 = 0; n2 < 4; n2++) {
#pragma unroll
            for (int r = 0; r < 4; r++) {
                int row = brow + wr * 128 + m * 16 + lb * 4 + r;
                int col = bcol + wc * 64 + n2 * 16 + la;
                float v = acc[m][n2][r] + bias[col];
                long oidx = (long)row * N + col;
                if (MODE == 0) {
                    outb[oidx] = __float2bfloat16(v);
                } else if (MODE == 1) {
                    float g = ada[nb * 1536 + 512 + col];
                    outf[oidx] = resid[oidx] + g * v;
                } else if (MODE == 2) {
                    // gelu_tanh(v) == v * sigmoid(2*0.7978845608*(v+0.044715 v^3))
                    float u2 = 1.5957691216057308f * (v + 0.044715f * v * v * v);
                    outb[oidx] = __float2bfloat16(v / (1.0f + __expf(-u2)));
                } else {
                    float g = ada[nb * 1536 + 1280 + col];
                    outf[oidx] = outf[oidx] + g * v;
                }
            }
        }
    }
}

// ---------------- MFMA window attention ------------------------------------
// Block = 4 waves, all same head h (shared bias LDS); wave w owns one window.
__global__ __launch_bounds__(256) void win_attn_mfma(const __hip_bfloat16* __restrict__ qkv,
                                                     const float* __restrict__ rpb,
                                                     __hip_bfloat16* __restrict__ out) {
    __shared__ float bias_s[64 * 64];   // 16 KB, shared (one head per block)
    __shared__ u16 vt[4][32 * 72];      // per-wave V^T, pad 72
    __shared__ u16 pl[4][64 * 72];      // per-wave P, pad 72

    int tid = threadIdx.x;
    int bid = blockIdx.x;
    int h = bid & 7;
    int w = tid >> 6;
    int lane = tid & 63;
    int la = lane & 15, lb = lane >> 4;
    int win = (bid >> 3) * 4 + w;
    int n = win >> 6;
    int wh = (win >> 3) & 7;
    int ww = win & 7;
    long base_row = (long)n * 4096 + (long)(wh * 8) * 64 + ww * 8;

    // bias table for this head
    for (int i = tid; i < 4096; i += 256) {
        int t = i >> 6, j = i & 63;
        int idx = ((t >> 3) - (j >> 3) + 7) * 15 + ((t & 7) - (j & 7) + 7);
        bias_s[i] = rpb[idx * 8 + h];
    }

    const u16* qg = (const u16*)qkv;

    // Q/K fragments (A: row=la, kchunk=lb*8 ; B: col=la, kchunk=lb*8)
    s16x8 qf[4], kf[4];
#pragma unroll
    for (int rt = 0; rt < 4; rt++) {
        int t = rt * 16 + la;
        long sr = base_row + (t >> 3) * 64 + (t & 7);
        qf[rt] = *(const s16x8*)(qg + sr * 768 + h * 32 + lb * 8);
        kf[rt] = *(const s16x8*)(qg + sr * 768 + 256 + h * 32 + lb * 8);
    }
    // stage V^T into LDS: vt[d][t]
#pragma unroll
    for (int g = 0; g < 4; g++) {
        int t = g * 16 + la;
        long sr = base_row + (t >> 3) * 64 + (t & 7);
        u16x8 vv = *(const u16x8*)(qg + sr * 768 + 512 + h * 32 + lb * 8);
#pragma unroll
        for (int e = 0; e < 8; e++) vt[w][(lb * 8 + e) * 72 + t] = vv[e];
    }

    // S = Q K^T
    f32x4 sa[4][4];
    f32x4 zero = {};
#pragma unroll
    for (int rt = 0; rt < 4; rt++)
#pragma unroll
        for (int ct = 0; ct < 4; ct++)
            sa[rt][ct] = __builtin_amdgcn_mfma_f32_16x16x32_bf16(qf[rt], kf[ct], zero, 0, 0, 0);

    __syncthreads();   // bias_s + vt ready

    // softmax (rows: t = rt*16 + lb*4 + r; keys: j = ct*16 + la)
    float rls[4][4];
#pragma unroll
    for (int rt = 0; rt < 4; rt++) {
#pragma unroll
        for (int r = 0; r < 4; r++) {
            int t = rt * 16 + lb * 4 + r;
            float v0 = sa[rt][0][r] * 0.17677669529663687f + bias_s[t * 64 + 0 * 16 + la];
            float v1 = sa[rt][1][r] * 0.17677669529663687f + bias_s[t * 64 + 1 * 16 + la];
            float v2 = sa[rt][2][r] * 0.17677669529663687f + bias_s[t * 64 + 2 * 16 + la];
            float v3 = sa[rt][3][r] * 0.17677669529663687f + bias_s[t * 64 + 3 * 16 + la];
            float mx = fmaxf(fmaxf(v0, v1), fmaxf(v2, v3));
#pragma unroll
            for (int o = 1; o < 16; o <<= 1) mx = fmaxf(mx, __shfl_xor(mx, o, 64));
            float p0 = __expf(v0 - mx), p1 = __expf(v1 - mx);
            float p2 = __expf(v2 - mx), p3 = __expf(v3 - mx);
            float sum = (p0 + p1) + (p2 + p3);
#pragma unroll
            for (int o = 1; o < 16; o <<= 1) sum += __shfl_xor(sum, o, 64);
            sa[rt][0][r] = p0; sa[rt][1][r] = p1; sa[rt][2][r] = p2; sa[rt][3][r] = p3;
            rls[rt][r] = 1.0f / sum;
        }
    }

    // P -> LDS (bf16), layout pl[t][j]
#pragma unroll
    for (int rt = 0; rt < 4; rt++)
#pragma unroll
        for (int ct = 0; ct < 4; ct++)
#pragma unroll
            for (int r = 0; r < 4; r++)
                pl[w][(rt * 16 + lb * 4 + r) * 72 + ct * 16 + la] = f2bf(sa[rt][ct][r]);

    __syncthreads();   // pl/vt writes drained

    // O = P V
    f32x4 oa[4][2] = {};
#pragma unroll
    for (int ks = 0; ks < 2; ks++) {
        s16x8 vf[2];
#pragma unroll
        for (int dt = 0; dt < 2; dt++)
            vf[dt] = *(const s16x8*)&vt[w][(dt * 16 + la) * 72 + ks * 32 + lb * 8];
#pragma unroll
        for (int rt = 0; rt < 4; rt++) {
            s16x8 pf = *(const s16x8*)&pl[w][(rt * 16 + la) * 72 + ks * 32 + lb * 8];
#pragma unroll
            for (int dt = 0; dt < 2; dt++)
                oa[rt][dt] = __builtin_amdgcn_mfma_f32_16x16x32_bf16(pf, vf[dt], oa[rt][dt], 0, 0, 0);
        }
    }

    // write O (normalize by 1/lsum here; lane row mapping matches S)
#pragma unroll
    for (int rt = 0; rt < 4; rt++) {
#pragma unroll
        for (int r = 0; r < 4; r++) {
            int t = rt * 16 + lb * 4 + r;
            long sr = base_row + (t >> 3) * 64 + (t & 7);
#pragma unroll
            for (int dt = 0; dt < 2; dt++) {
                int d = dt * 16 + la;
                out[sr * 256 + h * 32 + d] = __float2bfloat16(oa[rt][dt][r] * rls[rt][r]);
            }
        }
    }
}

// ---------------------------------------------------------------------------
extern "C" void kernel_launch(void* const* d_in, const int* in_sizes, int n_in,
                              void* d_out, int out_size, void* d_ws, size_t ws_size,
                              hipStream_t stream) {
    const float* x_seq  = (const float*)d_in[0];
    const float* c      = (const float*)d_in[1];
    const float* qkv_w  = (const float*)d_in[2];
    const float* qkv_b  = (const float*)d_in[3];
    const float* proj_w = (const float*)d_in[4];
    const float* proj_b = (const float*)d_in[5];
    const float* rpb    = (const float*)d_in[6];
    const float* ada_w  = (const float*)d_in[7];
    const float* ada_b  = (const float*)d_in[8];
    const float* fc1_w  = (const float*)d_in[9];
    const float* fc1_b  = (const float*)d_in[10];
    const float* fc2_w  = (const float*)d_in[11];
    const float* fc2_b  = (const float*)d_in[12];

    char* ws = (char*)d_ws;
    float* ada             = (float*)ws;                       // 96 KB
    __hip_bfloat16* qkv_wt = (__hip_bfloat16*)(ws + 131072);   // 768x256 bf16
    __hip_bfloat16* proj_wt= (__hip_bfloat16*)(ws + 524288);   // 256x256
    __hip_bfloat16* fc1_wt = (__hip_bfloat16*)(ws + 655360);   // 1024x256
    __hip_bfloat16* fc2_wt = (__hip_bfloat16*)(ws + 1179648);  // 256x1024
    __hip_bfloat16* bufA   = (__hip_bfloat16*)(ws + 2097152);  // 32 MB: xb / attn_out / xmlp
    __hip_bfloat16* bufB   = (__hip_bfloat16*)(ws + 35651584); // 128 MB: qkv / h1
    float* outf = (float*)d_out;

    wconv_t<<<(256 * 768 + 255) / 256, 256, 0, stream>>>(qkv_w, qkv_wt, 256, 768);
    wconv_t<<<(256 * 256 + 255) / 256, 256, 0, stream>>>(proj_w, proj_wt, 256, 256);
    wconv_t<<<(256 * 1024 + 255) / 256, 256, 0, stream>>>(fc1_w, fc1_wt, 256, 1024);
    wconv_t<<<(1024 * 256 + 255) / 256, 256, 0, stream>>>(fc2_w, fc2_wt, 1024, 256);

    ada_kernel<<<6, 256, 0, stream>>>(c, ada_w, ada_b, ada);

    // x_win LN+modulate (MSA) -> bufA (bf16)
    ln_mod<<<TTOT / 4, 256, 0, stream>>>(x_seq, ada, 0, 256, bufA);

    // qkv = bufA @ qkv_w + b -> bufB (bf16, 65536 x 768)
    gemm_bt<0><<<3 * 256, 512, 0, stream>>>(bufA, qkv_wt, qkv_b, nullptr, ada,
                                            nullptr, bufB, TTOT, 768, 256, 3);
    // window attention -> bufA (bf16, 65536 x 256)
    win_attn_mfma<<<2048, 256, 0, stream>>>(bufB, rpb, bufA);

    // out1 = x_seq + g_msa * (attn @ proj_w + b) -> d_out (f32)
    gemm_bt<1><<<1 * 256, 512, 0, stream>>>(bufA, proj_wt, proj_b, x_seq, ada,
                                            outf, nullptr, TTOT, 256, 256, 1);
    // LN+modulate (MLP) -> bufA (bf16)
    ln_mod<<<TTOT / 4, 256, 0, stream>>>(outf, ada, 768, 1024, bufA);

    // h1 = gelu(bufA @ fc1_w + b) -> bufB (bf16, 65536 x 1024)
    gemm_bt<2><<<4 * 256, 512, 0, stream>>>(bufA, fc1_wt, fc1_b, nullptr, ada,
                                            nullptr, bufB, TTOT, 1024, 256, 4);
    // out = out1 + g_mlp * (h1 @ fc2_w + b) -> d_out (f32)
    gemm_bt<3><<<1 * 256, 512, 0, stream>>>(bufB, fc2_wt, fc2_b, nullptr, ada,
                                            outf, nullptr, TTOT, 256, 1024, 1);
}